// Round 1
// baseline (257.733 us; speedup 1.0000x reference)
//
#include <hip/hip_runtime.h>
#include <stdint.h>

#define N_NODES 8192
#define D_IN    512
#define D_OUT   64
#define GAT_ALPHA 0.2f

typedef __attribute__((ext_vector_type(8))) short short8v;
typedef __attribute__((ext_vector_type(4))) float f32x4;

__device__ __forceinline__ unsigned short f2bf_rne(float f) {
    unsigned u = __float_as_uint(f);
    unsigned r = u + 0x7FFFu + ((u >> 16) & 1u);
    return (unsigned short)(r >> 16);
}
__device__ __forceinline__ float bf2f(unsigned short s) {
    return __uint_as_float(((unsigned)s) << 16);
}

// ---------------- Kernel A1: Wh = h @ W, s1 = Wh@a1, s2 = Wh@a2, S2max ----
__global__ __launch_bounds__(256) void k_wh(
    const float* __restrict__ h, const float* __restrict__ W,
    const float* __restrict__ a, float* __restrict__ Wh,
    float* __restrict__ s1, float* __restrict__ s2,
    unsigned* __restrict__ s2key)
{
    __shared__ float Wl[D_IN * D_OUT];   // 128 KB
    const int tid = threadIdx.x;
    for (int x = tid * 4; x < D_IN * D_OUT; x += 256 * 4)
        *(f32x4*)&Wl[x] = *(const f32x4*)&W[x];
    __syncthreads();

    const int lane = tid & 63;
    const int wv   = tid >> 6;
    const int i0 = blockIdx.x * 32 + wv * 8;

    float acc[8];
#pragma unroll
    for (int r = 0; r < 8; r++) acc[r] = 0.f;

    for (int k = 0; k < D_IN; k += 4) {
        const float w0 = Wl[(k + 0) * D_OUT + lane];
        const float w1 = Wl[(k + 1) * D_OUT + lane];
        const float w2 = Wl[(k + 2) * D_OUT + lane];
        const float w3 = Wl[(k + 3) * D_OUT + lane];
#pragma unroll
        for (int r = 0; r < 8; r++) {
            const float4 h4 = *(const float4*)(h + (size_t)(i0 + r) * D_IN + k);
            acc[r] = fmaf(h4.x, w0, acc[r]);
            acc[r] = fmaf(h4.y, w1, acc[r]);
            acc[r] = fmaf(h4.z, w2, acc[r]);
            acc[r] = fmaf(h4.w, w3, acc[r]);
        }
    }

    const float a1v = a[lane];
    const float a2v = a[D_OUT + lane];
#pragma unroll
    for (int r = 0; r < 8; r++) {
        const int i = i0 + r;
        Wh[(size_t)i * D_OUT + lane] = acc[r];
        float p1 = acc[r] * a1v;
        float p2 = acc[r] * a2v;
#pragma unroll
        for (int off = 32; off; off >>= 1) {
            p1 += __shfl_xor(p1, off, 64);
            p2 += __shfl_xor(p2, off, 64);
        }
        if (lane == 0) {
            s1[i] = p1;
            s2[i] = p2;
            unsigned u = __float_as_uint(p2);
            unsigned key = (u & 0x80000000u) ? ~u : (u | 0x80000000u);
            atomicMax(s2key, key);
        }
    }
}

// ---------------- Kernel A2: WhT[o][j] = bf16(Wh[j][o]) ---------------------
__global__ __launch_bounds__(256) void k_tr(
    const float* __restrict__ Wh, unsigned short* __restrict__ WhT)
{
    __shared__ float t[64][65];
    const int j0 = blockIdx.x * 64;
#pragma unroll
    for (int e = 0; e < 16; e++) {
        int idx = e * 256 + threadIdx.x;
        int jl = idx >> 6, o = idx & 63;
        t[jl][o] = Wh[(size_t)(j0 + jl) * D_OUT + o];
    }
    __syncthreads();
    const int o = threadIdx.x >> 2;
    const int c = (threadIdx.x & 3) * 16;
    unsigned short tmp[16];
#pragma unroll
    for (int e = 0; e < 16; e++) tmp[e] = f2bf_rne(t[c + e][o]);
    *(short8v*)(WhT + (size_t)o * N_NODES + j0 + c)     = *(short8v*)&tmp[0];
    *(short8v*)(WhT + (size_t)o * N_NODES + j0 + c + 8) = *(short8v*)&tmp[8];
}

// ---------------- Kernel B: fused masked softmax + attn @ Wh + elu ---------
__global__ __launch_bounds__(512) void k_attn(
    const int* __restrict__ adj, const unsigned short* __restrict__ WhT,
    const float* __restrict__ s1, const float* __restrict__ s2,
    const unsigned* __restrict__ s2key, const float* __restrict__ bias,
    float* __restrict__ out)
{
    __shared__ float num_lds[8][16][D_OUT];
    __shared__ float den_lds[8][16];

    const int tid = threadIdx.x;
    const int w   = tid >> 6;        // wave = j-group 0..7
    const int l   = tid & 63;
    const int r   = l & 15;          // row within 16-row block / B-frag col
    const int kg  = l >> 4;          // k-group 0..3
    const int i0  = blockIdx.x * 16;
    const int i   = i0 + r;

    // decode S2max (ordered-uint encoded by k_wh)
    const unsigned key = *s2key;
    const unsigned ub  = (key & 0x80000000u) ? (key & 0x7FFFFFFFu) : ~key;
    const float S2max  = __uint_as_float(ub);

    const float s1r = s1[i];
    const float x0  = s1r + S2max;
    const float m   = fmaxf(x0, GAT_ALPHA * x0);   // valid upper bound of row max

    f32x4 acc[4] = {};
    float den = 0.f;

    const size_t adj_row = (size_t)i * N_NODES;
    const unsigned short* wt0 = WhT + (size_t)(0 * 16 + r) * N_NODES;
    const unsigned short* wt1 = WhT + (size_t)(1 * 16 + r) * N_NODES;
    const unsigned short* wt2 = WhT + (size_t)(2 * 16 + r) * N_NODES;
    const unsigned short* wt3 = WhT + (size_t)(3 * 16 + r) * N_NODES;

    for (int step = 0; step < 32; step++) {
        const int j0 = w * 1024 + step * 32;
        const int jj = j0 + kg * 8;

        const int4   adjA = *(const int4*)(adj + adj_row + jj);
        const int4   adjB = *(const int4*)(adj + adj_row + jj + 4);
        const float4 s2A  = *(const float4*)(s2 + jj);
        const float4 s2B  = *(const float4*)(s2 + jj + 4);
        const short8v b0  = *(const short8v*)(wt0 + jj);
        const short8v b1  = *(const short8v*)(wt1 + jj);
        const short8v b2  = *(const short8v*)(wt2 + jj);
        const short8v b3  = *(const short8v*)(wt3 + jj);

        const float s2v[8] = { s2A.x, s2A.y, s2A.z, s2A.w,
                               s2B.x, s2B.y, s2B.z, s2B.w };
        const int   av[8]  = { adjA.x, adjA.y, adjA.z, adjA.w,
                               adjB.x, adjB.y, adjB.z, adjB.w };

        short8v af;
#pragma unroll
        for (int e = 0; e < 8; e++) {
            const float x  = s1r + s2v[e];
            const float xl = fmaxf(x, GAT_ALPHA * x);
            const float p  = (av[e] > 0) ? __expf(xl - m) : 0.f;
            const unsigned short q = f2bf_rne(p);
            af[e] = (short)q;
            den += bf2f(q);
        }

        acc[0] = __builtin_amdgcn_mfma_f32_16x16x32_bf16(af, b0, acc[0], 0, 0, 0);
        acc[1] = __builtin_amdgcn_mfma_f32_16x16x32_bf16(af, b1, acc[1], 0, 0, 0);
        acc[2] = __builtin_amdgcn_mfma_f32_16x16x32_bf16(af, b2, acc[2], 0, 0, 0);
        acc[3] = __builtin_amdgcn_mfma_f32_16x16x32_bf16(af, b3, acc[3], 0, 0, 0);
    }

    // wave-level denominator: sum over the 4 k-groups (rows preserved)
    den += __shfl_xor(den, 16, 64);
    den += __shfl_xor(den, 32, 64);

    // write wave partials
#pragma unroll
    for (int c = 0; c < 4; c++)
#pragma unroll
        for (int q = 0; q < 4; q++)
            num_lds[w][kg * 4 + q][c * 16 + r] = acc[c][q];
    if (l < 16) den_lds[w][l] = den;
    __syncthreads();

    // combine 8 wave partials, epilogue
#pragma unroll
    for (int rep = 0; rep < 2; rep++) {
        const int eidx = rep * 512 + tid;
        const int il = eidx >> 6, o = eidx & 63;
        float nsum = 0.f, dsum = 0.f;
#pragma unroll
        for (int ww = 0; ww < 8; ww++) {
            nsum += num_lds[ww][il][o];
            dsum += den_lds[ww][il];
        }
        if (dsum == 0.f) dsum = 1.f;
        const float v = nsum / dsum + bias[o];
        out[(size_t)(i0 + il) * D_OUT + o] = v > 0.f ? v : expm1f(v);
    }
}

extern "C" void kernel_launch(void* const* d_in, const int* in_sizes, int n_in,
                              void* d_out, int out_size, void* d_ws, size_t ws_size,
                              hipStream_t stream)
{
    const float* h    = (const float*)d_in[0];
    const int*   adj  = (const int*)d_in[1];
    const float* W    = (const float*)d_in[2];
    const float* a    = (const float*)d_in[3];
    const float* bias = (const float*)d_in[4];
    float* out = (float*)d_out;

    char* ws = (char*)d_ws;
    float*          Wh    = (float*)ws;                                  // 2 MB
    unsigned short* WhT   = (unsigned short*)(ws + (size_t)N_NODES * D_OUT * 4); // 1 MB
    float*          s1    = (float*)(ws + (size_t)3 * 1024 * 1024);      // 32 KB
    float*          s2    = s1 + N_NODES;                                // 32 KB
    unsigned*       s2key = (unsigned*)(s2 + N_NODES);                   // 4 B

    hipMemsetAsync(s2key, 0, 4, stream);
    k_wh<<<N_NODES / 32, 256, 0, stream>>>(h, W, a, Wh, s1, s2, s2key);
    k_tr<<<N_NODES / 64, 256, 0, stream>>>(Wh, WhT);
    k_attn<<<N_NODES / 16, 512, 0, stream>>>(adj, WhT, s1, s2, s2key, bias, out);
}

// Round 2
// 213.648 us; speedup vs baseline: 1.2063x; 1.2063x over previous
//
#include <hip/hip_runtime.h>
#include <stdint.h>

#define N_NODES 8192
#define D_IN    512
#define D_OUT   64
#define GAT_ALPHA 0.2f

typedef __attribute__((ext_vector_type(8))) short short8v;
typedef __attribute__((ext_vector_type(4))) float f32x4;

__device__ __forceinline__ unsigned short f2bf_rne(float f) {
    unsigned u = __float_as_uint(f);
    unsigned r = u + 0x7FFFu + ((u >> 16) & 1u);
    return (unsigned short)(r >> 16);
}
__device__ __forceinline__ float bf2f(unsigned short s) {
    return __uint_as_float(((unsigned)s) << 16);
}

// ---- Kernel A1: Wh = h @ W, s1 = Wh@a1, s2 = Wh@a2, S2max (1 row/wave) ----
__global__ __launch_bounds__(256) void k_wh(
    const float* __restrict__ h, const float* __restrict__ W,
    const float* __restrict__ a, float* __restrict__ Wh,
    float* __restrict__ s1, float* __restrict__ s2,
    unsigned* __restrict__ s2key)
{
    const int lane = threadIdx.x & 63;
    const int wv   = threadIdx.x >> 6;
    const int i    = blockIdx.x * 4 + wv;

    const float* hrow = h + (size_t)i * D_IN;
    float acc = 0.f;
#pragma unroll 4
    for (int k = 0; k < D_IN; k += 4) {
        const float4 h4 = *(const float4*)(hrow + k);  // wave-uniform -> s_load
        acc = fmaf(h4.x, W[(k + 0) * D_OUT + lane], acc);
        acc = fmaf(h4.y, W[(k + 1) * D_OUT + lane], acc);
        acc = fmaf(h4.z, W[(k + 2) * D_OUT + lane], acc);
        acc = fmaf(h4.w, W[(k + 3) * D_OUT + lane], acc);
    }
    Wh[(size_t)i * D_OUT + lane] = acc;

    float p1 = acc * a[lane];
    float p2 = acc * a[D_OUT + lane];
#pragma unroll
    for (int off = 32; off; off >>= 1) {
        p1 += __shfl_xor(p1, off, 64);
        p2 += __shfl_xor(p2, off, 64);
    }
    if (lane == 0) {
        s1[i] = p1;
        s2[i] = p2;
        unsigned u = __float_as_uint(p2);
        unsigned key = (u & 0x80000000u) ? ~u : (u | 0x80000000u);
        atomicMax(s2key, key);
    }
}

// ---- Kernel A2: WhT[o][j] = bf16(Wh[j][o]) --------------------------------
__global__ __launch_bounds__(256) void k_tr(
    const float* __restrict__ Wh, unsigned short* __restrict__ WhT)
{
    __shared__ float t[64][65];
    const int j0 = blockIdx.x * 64;
#pragma unroll
    for (int e = 0; e < 16; e++) {
        int idx = e * 256 + threadIdx.x;
        int jl = idx >> 6, o = idx & 63;
        t[jl][o] = Wh[(size_t)(j0 + jl) * D_OUT + o];
    }
    __syncthreads();
    const int o = threadIdx.x >> 2;
    const int c = (threadIdx.x & 3) * 16;
    unsigned short tmp[16];
#pragma unroll
    for (int e = 0; e < 16; e++) tmp[e] = f2bf_rne(t[c + e][o]);
    *(short8v*)(WhT + (size_t)o * N_NODES + j0 + c)     = *(short8v*)&tmp[0];
    *(short8v*)(WhT + (size_t)o * N_NODES + j0 + c + 8) = *(short8v*)&tmp[8];
}

// ---- Kernel B: fused masked softmax + attn @ Wh + elu ---------------------
// Block = 16 rows, 512 threads (8 waves). Per macro-step: stage adj[16][256]
// into LDS with coalesced loads (1KB contiguous per row), waves compute
// disjoint 32-col MFMA k-steps from LDS.
__global__ __launch_bounds__(512) void k_attn(
    const int* __restrict__ adj, const unsigned short* __restrict__ WhT,
    const float* __restrict__ s1, const float* __restrict__ s2,
    const unsigned* __restrict__ s2key, const float* __restrict__ bias,
    float* __restrict__ out)
{
    __shared__ int   adj_lds[16][260];      // +4 pad -> 2-way conflicts only
    __shared__ float s2_lds[256];
    __shared__ float num_lds[8][16][D_OUT];
    __shared__ float den_lds[8][16];

    const int tid = threadIdx.x;
    const int w   = tid >> 6;
    const int l   = tid & 63;
    const int r   = l & 15;
    const int kg  = l >> 4;
    const int i0  = blockIdx.x * 16;
    const int i   = i0 + r;

    // staging role: row srow, 32B chunk at scol (coalesced per row)
    const int srow = tid >> 5;
    const int scol = (tid & 31) * 8;
    const int* gsrc = adj + (size_t)(i0 + srow) * N_NODES + scol;

    const unsigned key = *s2key;
    const unsigned ub  = (key & 0x80000000u) ? (key & 0x7FFFFFFFu) : ~key;
    const float S2max  = __uint_as_float(ub);

    const float s1r = s1[i];
    const float x0  = s1r + S2max;
    const float m   = fmaxf(x0, GAT_ALPHA * x0);   // upper bound of row max

    f32x4 acc[4] = {};
    float den = 0.f;

    const int ccol = w * 32 + kg * 8;
    const unsigned short* wt0 = WhT + (size_t)(0 * 16 + r) * N_NODES + ccol;
    const unsigned short* wt1 = WhT + (size_t)(1 * 16 + r) * N_NODES + ccol;
    const unsigned short* wt2 = WhT + (size_t)(2 * 16 + r) * N_NODES + ccol;
    const unsigned short* wt3 = WhT + (size_t)(3 * 16 + r) * N_NODES + ccol;

    // prologue: tile 0 into regs
    int4 rA = *(const int4*)(gsrc);
    int4 rB = *(const int4*)(gsrc + 4);
    float4 rS;
    if (tid < 64) rS = *(const float4*)(s2 + tid * 4);

    for (int mt = 0; mt < 32; ++mt) {
        const int jbase = mt * 256;

        *(int4*)&adj_lds[srow][scol]     = rA;
        *(int4*)&adj_lds[srow][scol + 4] = rB;
        if (tid < 64) *(float4*)&s2_lds[tid * 4] = rS;
        __syncthreads();

        if (mt + 1 < 32) {   // prefetch next tile (overlaps compute below)
            rA = *(const int4*)(gsrc + (mt + 1) * 256);
            rB = *(const int4*)(gsrc + (mt + 1) * 256 + 4);
            if (tid < 64) rS = *(const float4*)(s2 + jbase + 256 + tid * 4);
        }

        const int4   aA = *(const int4*)&adj_lds[r][ccol];
        const int4   aB = *(const int4*)&adj_lds[r][ccol + 4];
        const float4 sA = *(const float4*)&s2_lds[ccol];
        const float4 sB = *(const float4*)&s2_lds[ccol + 4];
        const short8v b0 = *(const short8v*)(wt0 + jbase);
        const short8v b1 = *(const short8v*)(wt1 + jbase);
        const short8v b2 = *(const short8v*)(wt2 + jbase);
        const short8v b3 = *(const short8v*)(wt3 + jbase);

        const float s2v[8] = { sA.x, sA.y, sA.z, sA.w, sB.x, sB.y, sB.z, sB.w };
        const int   av[8]  = { aA.x, aA.y, aA.z, aA.w, aB.x, aB.y, aB.z, aB.w };

        short8v af;
#pragma unroll
        for (int e = 0; e < 8; e++) {
            const float x  = s1r + s2v[e];
            const float xl = fmaxf(x, GAT_ALPHA * x);
            const float p  = (av[e] > 0) ? __expf(xl - m) : 0.f;
            const unsigned short q = f2bf_rne(p);
            af[e] = (short)q;
            den += bf2f(q);
        }

        acc[0] = __builtin_amdgcn_mfma_f32_16x16x32_bf16(af, b0, acc[0], 0, 0, 0);
        acc[1] = __builtin_amdgcn_mfma_f32_16x16x32_bf16(af, b1, acc[1], 0, 0, 0);
        acc[2] = __builtin_amdgcn_mfma_f32_16x16x32_bf16(af, b2, acc[2], 0, 0, 0);
        acc[3] = __builtin_amdgcn_mfma_f32_16x16x32_bf16(af, b3, acc[3], 0, 0, 0);

        __syncthreads();
    }

    // denominator: sum the 4 k-groups (rows preserved)
    den += __shfl_xor(den, 16, 64);
    den += __shfl_xor(den, 32, 64);

#pragma unroll
    for (int c = 0; c < 4; c++)
#pragma unroll
        for (int q = 0; q < 4; q++)
            num_lds[w][kg * 4 + q][c * 16 + r] = acc[c][q];
    if (l < 16) den_lds[w][l] = den;
    __syncthreads();

#pragma unroll
    for (int rep = 0; rep < 2; rep++) {
        const int eidx = rep * 512 + tid;
        const int il = eidx >> 6, o = eidx & 63;
        float nsum = 0.f, dsum = 0.f;
#pragma unroll
        for (int ww = 0; ww < 8; ww++) {
            nsum += num_lds[ww][il][o];
            dsum += den_lds[ww][il];
        }
        if (dsum == 0.f) dsum = 1.f;
        const float v = nsum / dsum + bias[o];
        out[(size_t)(i0 + il) * D_OUT + o] = v > 0.f ? v : expm1f(v);
    }
}

extern "C" void kernel_launch(void* const* d_in, const int* in_sizes, int n_in,
                              void* d_out, int out_size, void* d_ws, size_t ws_size,
                              hipStream_t stream)
{
    const float* h    = (const float*)d_in[0];
    const int*   adj  = (const int*)d_in[1];
    const float* W    = (const float*)d_in[2];
    const float* a    = (const float*)d_in[3];
    const float* bias = (const float*)d_in[4];
    float* out = (float*)d_out;

    char* ws = (char*)d_ws;
    float*          Wh    = (float*)ws;                                          // 2 MB
    unsigned short* WhT   = (unsigned short*)(ws + (size_t)N_NODES * D_OUT * 4); // 1 MB
    float*          s1    = (float*)(ws + (size_t)3 * 1024 * 1024);              // 32 KB
    float*          s2    = s1 + N_NODES;                                        // 32 KB
    unsigned*       s2key = (unsigned*)(s2 + N_NODES);                           // 4 B

    hipMemsetAsync(s2key, 0, 4, stream);
    k_wh<<<N_NODES / 4, 256, 0, stream>>>(h, W, a, Wh, s1, s2, s2key);
    k_tr<<<N_NODES / 64, 256, 0, stream>>>(Wh, WhT);
    k_attn<<<N_NODES / 16, 512, 0, stream>>>(adj, WhT, s1, s2, s2key, bias, out);
}